// Round 8
// baseline (416.092 us; speedup 1.0000x reference)
//
#include <hip/hip_runtime.h>
#include <hip/hip_bf16.h>

#define N_NODES 16384
#define F_IN    512
#define N_EDGE  524288
#define H1      32
#define H2      16

typedef float f32x4 __attribute__((ext_vector_type(4)));
typedef short bf16x8 __attribute__((ext_vector_type(8)));

// ---------------- workspace layout (in 4-byte words) ----------------
#define OFF_CNT     0u          // u32 [16384]
#define OFF_ROWPTR  16448u      // u32 [16385]
#define OFF_CURSOR  32896u      // u32 [16384]
#define OFF_SRCS    49344u      // i32 [E]
#define OFF_DINV    573632u     // f32 [16384]
#define OFF_XW1     590080u     // f32 [N*32]; reused as zhl bf16 [N*32] after conv1
#define OFF_XW23    1114368u    // f32 [N*32]  (cols 0..15 = h1@W2, 16..31 = h1@W3)

__device__ __forceinline__ float sigf(float x) {
    float e = __expf(-x);
    return __builtin_amdgcn_rcpf(1.0f + e);
}

__device__ __forceinline__ unsigned short bf16_rne(float f) {
    unsigned u = __float_as_uint(f);
    return (unsigned short)((u + 0x7FFFu + ((u >> 16) & 1u)) >> 16);
}

// K1: histogram of dst
__global__ __launch_bounds__(256) void hist_k(const int* __restrict__ ei,
                                              unsigned* __restrict__ cnt) {
    int e = blockIdx.x * 256 + threadIdx.x;
    atomicAdd(&cnt[ei[N_EDGE + e]], 1u);
}

// K2: exclusive scan of cnt -> rowptr/cursor; dinv = rsqrt(cnt+1)
__global__ __launch_bounds__(1024) void scan_k(const unsigned* __restrict__ cnt,
                                               unsigned* __restrict__ rowptr,
                                               unsigned* __restrict__ cursor,
                                               float* __restrict__ dinv) {
    const int t = threadIdx.x;           // 1024 threads, 16 elems each
    unsigned vals[16];
    const uint4* c4 = (const uint4*)cnt;
#pragma unroll
    for (int i = 0; i < 4; ++i) {
        uint4 v = c4[t * 4 + i];
        vals[i * 4 + 0] = v.x; vals[i * 4 + 1] = v.y;
        vals[i * 4 + 2] = v.z; vals[i * 4 + 3] = v.w;
    }
    unsigned loc[16], s = 0;
#pragma unroll
    for (int i = 0; i < 16; ++i) { loc[i] = s; s += vals[i]; }

    const int lane = t & 63, w = t >> 6;       // 16 waves
    unsigned v = s;
#pragma unroll
    for (int off = 1; off < 64; off <<= 1) {
        unsigned u = __shfl_up(v, off);
        if (lane >= off) v += u;
    }
    __shared__ unsigned wtot[16];
    if (lane == 63) wtot[w] = v;
    __syncthreads();
    if (t == 0) {
        unsigned run = 0;
#pragma unroll
        for (int i = 0; i < 16; ++i) { unsigned x = wtot[i]; wtot[i] = run; run += x; }
        rowptr[N_NODES] = run;   // == E
    }
    __syncthreads();
    unsigned base = wtot[w] + v - s;    // exclusive prefix for this thread's chunk
#pragma unroll
    for (int i = 0; i < 16; ++i) {
        unsigned rp = base + loc[i];
        rowptr[t * 16 + i] = rp;
        cursor[t * 16 + i] = rp;
        dinv[t * 16 + i] = rsqrtf((float)(vals[i] + 1u));
    }
}

// K3: counting-sort fill: srcs grouped by dst
__global__ __launch_bounds__(256) void fill_k(const int* __restrict__ ei,
                                              unsigned* __restrict__ cursor,
                                              int* __restrict__ srcs) {
    int e = blockIdx.x * 256 + threadIdx.x;
    int d = ei[N_EDGE + e];
    unsigned p = atomicAdd(&cursor[d], 1u);
    srcs[p] = ei[e];
}

// K4: xw1 = x @ W1   [16384,512]x[512,32]
__global__ __launch_bounds__(256) void gemm1_k(const float* __restrict__ x,
                                               const float* __restrict__ W,
                                               float* __restrict__ xw) {
    int tid = blockIdx.x * 256 + threadIdx.x;
    int row = tid >> 3, cq = tid & 7;        // col quad
    const float4* x4 = (const float4*)(x + (size_t)row * F_IN);
    const float4* W4 = (const float4*)W;     // W[k][c]: 8 float4 per k-row
    float ax = 0.f, ay = 0.f, az = 0.f, aw = 0.f;
#pragma unroll 4
    for (int k4 = 0; k4 < F_IN / 4; ++k4) {
        float4 xv = x4[k4];
        float4 w0 = W4[(size_t)(4 * k4 + 0) * 8 + cq];
        float4 w1 = W4[(size_t)(4 * k4 + 1) * 8 + cq];
        float4 w2 = W4[(size_t)(4 * k4 + 2) * 8 + cq];
        float4 w3 = W4[(size_t)(4 * k4 + 3) * 8 + cq];
        ax = fmaf(xv.x, w0.x, ax); ay = fmaf(xv.x, w0.y, ay);
        az = fmaf(xv.x, w0.z, az); aw = fmaf(xv.x, w0.w, aw);
        ax = fmaf(xv.y, w1.x, ax); ay = fmaf(xv.y, w1.y, ay);
        az = fmaf(xv.y, w1.z, az); aw = fmaf(xv.y, w1.w, aw);
        ax = fmaf(xv.z, w2.x, ax); ay = fmaf(xv.z, w2.y, ay);
        az = fmaf(xv.z, w2.z, az); aw = fmaf(xv.z, w2.w, aw);
        ax = fmaf(xv.w, w3.x, ax); ay = fmaf(xv.w, w3.y, ay);
        az = fmaf(xv.w, w3.z, az); aw = fmaf(xv.w, w3.w, aw);
    }
    float4 o; o.x = ax; o.y = ay; o.z = az; o.w = aw;
    ((float4*)xw)[(size_t)row * 8 + cq] = o;
}

// K5: conv1 gather (h1 in LDS) fused with xw23 = h1@[W2|W3] (interleaved table)
__global__ __launch_bounds__(256) void conv1_k(const float* __restrict__ xw1,
                                               const float* __restrict__ dinv,
                                               const int* __restrict__ srcs,
                                               const unsigned* __restrict__ rowptr,
                                               const float* __restrict__ b1,
                                               const float* __restrict__ W2,
                                               const float* __restrict__ W3,
                                               float* __restrict__ xw23) {
    const int t = threadIdx.x;
    const int node = blockIdx.x * 8 + (t >> 5);
    const int c = t & 31;
    unsigned e0 = rowptr[node], e1 = rowptr[node + 1];
    float sum = 0.f;
    for (unsigned e = e0; e < e1; ++e) {
        int s = srcs[e];
        sum = fmaf(xw1[(size_t)s * H1 + c], dinv[s], sum);
    }
    float di = dinv[node];
    float h = fmaf(di, sum, di * di * xw1[(size_t)node * H1 + c]) + b1[c];
    __shared__ float h1s[8][H1 + 1];
    h1s[t >> 5][c] = h;
    __syncthreads();
    const float* Wm = (c < H2) ? W2 : W3;
    int q = c & (H2 - 1);
    float acc = 0.f;
#pragma unroll
    for (int k = 0; k < H1; ++k) acc = fmaf(h1s[t >> 5][k], Wm[k * H2 + q], acc);
    xw23[(size_t)node * 32 + c] = acc;
}

// K6: conv2 gather -> mu, logvar; mu lanes also emit hi/lo bf16 into zhl
// (fused former split_k).
__global__ __launch_bounds__(256) void conv2_k(const float* __restrict__ xw23,
                                               const float* __restrict__ dinv,
                                               const int* __restrict__ srcs,
                                               const unsigned* __restrict__ rowptr,
                                               const float* __restrict__ b2,
                                               const float* __restrict__ b3,
                                               float* __restrict__ out_mu,
                                               float* __restrict__ out_lv,
                                               unsigned short* __restrict__ zhl) {
    const int t = threadIdx.x;
    const int node = blockIdx.x * 8 + (t >> 5);
    const int c = t & 31;
    const int q = c & (H2 - 1);
    unsigned e0 = rowptr[node], e1 = rowptr[node + 1];
    float sum = 0.f;
    for (unsigned e = e0; e < e1; ++e) {
        int s = srcs[e];
        sum = fmaf(xw23[(size_t)s * 32 + c], dinv[s], sum);
    }
    float di = dinv[node];
    float v = fmaf(di, sum, di * di * xw23[(size_t)node * 32 + c]) +
              ((c < H2) ? b2[q] : b3[q]);
    if (c < H2) {
        out_mu[(size_t)node * H2 + q] = v;
        unsigned short hb = bf16_rne(v);
        float hf = __uint_as_float((unsigned)hb << 16);
        unsigned short lb = bf16_rne(v - hf);
        zhl[(size_t)node * 32 + q] = hb;          // hi[0..15]
        zhl[(size_t)node * 32 + 16 + q] = lb;     // lo[0..15]
    } else {
        out_lv[(size_t)node * H2 + q] = v;
    }
}

// K7: adj = sigmoid(z z^T), wide-short tiles for DRAM page locality:
// each block = 32 rows x 4096 cols, so every row receives a 16KB sequential
// span per block (vs 512B with 128-wide tiles). Per wave: 16 fixed rows in
// B-regs, A-frags (cols) stream from L2 (1KB/instr coalesced), 2 chained
// hi/lo MFMAs, direct f32x4 stores. No LDS, no barriers.
__global__ __launch_bounds__(256) void adj_k(const unsigned short* __restrict__ zhl,
                                             float* __restrict__ out) {
    const int t = threadIdx.x;
    const int wave = t >> 6, lane = t & 63;
    const int lrow = lane & 15, g = lane >> 4;
    const int strip = blockIdx.x & 511;        // 512 strips of 32 rows
    const int chunk = blockIdx.x >> 9;         // 4 col-chunks of 4096
    const short* zs = (const short*)zhl;

    const int rbase = (strip << 5) + (wave >> 1) * 16;   // wave's 16 rows
    const int cbase = (chunk << 12) + (wave & 1) * 2048; // wave's 2048 cols

    // B-frags: the wave's 16 fixed rows, [hi_r|hi_r] and [lo_r|lo_r]
    const short* rb = zs + (size_t)(rbase + lrow) * 32;
    bf16x8 B1 = *(const bf16x8*)(rb + (g & 1) * 8);
    bf16x8 B2 = *(const bf16x8*)(rb + 16 + (g & 1) * 8);

    size_t rowoff = (size_t)(rbase + lrow) * N_NODES;

#pragma unroll 4
    for (int n = 0; n < 128; ++n) {
        int c = cbase + n * 16;
        // A-frag: cols c..c+15, full [hi|lo] K=32 packing
        bf16x8 A = *(const bf16x8*)(zs + (size_t)(c + lrow) * 32 + g * 8);
        f32x4 acc = (f32x4){0.f, 0.f, 0.f, 0.f};
        acc = __builtin_amdgcn_mfma_f32_16x16x32_bf16(A, B1, acc, 0, 0, 0);
        acc = __builtin_amdgcn_mfma_f32_16x16x32_bf16(A, B2, acc, 0, 0, 0);
        // D: lane&15 = N(row), g*4+reg = M(col) -> 4 consecutive cols
        f32x4 o;
        o.x = sigf(acc[0]); o.y = sigf(acc[1]);
        o.z = sigf(acc[2]); o.w = sigf(acc[3]);
        *(f32x4*)(out + rowoff + c + g * 4) = o;
    }
}

extern "C" void kernel_launch(void* const* d_in, const int* in_sizes, int n_in,
                              void* d_out, int out_size, void* d_ws, size_t ws_size,
                              hipStream_t stream) {
    const float* x  = (const float*)d_in[0];
    const int*   ei = (const int*)d_in[1];
    const float* W1 = (const float*)d_in[2];
    const float* b1 = (const float*)d_in[3];
    const float* W2 = (const float*)d_in[4];
    const float* b2 = (const float*)d_in[5];
    const float* W3 = (const float*)d_in[6];
    const float* b3 = (const float*)d_in[7];
    float* out = (float*)d_out;

    unsigned* ws   = (unsigned*)d_ws;
    unsigned* cnt    = ws + OFF_CNT;
    unsigned* rowptr = ws + OFF_ROWPTR;
    unsigned* cursor = ws + OFF_CURSOR;
    int*      srcs   = (int*)(ws + OFF_SRCS);
    float*    dinv   = (float*)(ws + OFF_DINV);
    float*    xw1    = (float*)(ws + OFF_XW1);
    float*    xw23   = (float*)(ws + OFF_XW23);
    unsigned short* zhl = (unsigned short*)(ws + OFF_XW1);  // reuse after conv1

    float* out_mu = out + (size_t)N_NODES * N_NODES;
    float* out_lv = out_mu + (size_t)N_NODES * H2;

    (void)hipMemsetAsync(cnt, 0, N_NODES * sizeof(unsigned), stream);
    hist_k<<<N_EDGE / 256, 256, 0, stream>>>(ei, cnt);
    scan_k<<<1, 1024, 0, stream>>>(cnt, rowptr, cursor, dinv);
    fill_k<<<N_EDGE / 256, 256, 0, stream>>>(ei, cursor, srcs);
    gemm1_k<<<(N_NODES * 8) / 256, 256, 0, stream>>>(x, W1, xw1);
    conv1_k<<<N_NODES / 8, 256, 0, stream>>>(xw1, dinv, srcs, rowptr, b1, W2, W3, xw23);
    conv2_k<<<N_NODES / 8, 256, 0, stream>>>(xw23, dinv, srcs, rowptr, b2, b3,
                                             out_mu, out_lv, zhl);
    adj_k<<<dim3(2048), 256, 0, stream>>>(zhl, out);
}

// Round 13
// 308.783 us; speedup vs baseline: 1.3475x; 1.3475x over previous
//
#include <hip/hip_runtime.h>
#include <hip/hip_bf16.h>

#define N_NODES 16384
#define F_IN    512
#define N_EDGE  524288
#define H1      32
#define H2      16

typedef float f32x4 __attribute__((ext_vector_type(4)));
typedef short bf16x8 __attribute__((ext_vector_type(8)));

// ---------------- workspace layout (in 4-byte words) ----------------
#define OFF_CNT     0u          // u32 [16384]
#define OFF_ROWPTR  16448u      // u32 [16385]
#define OFF_CURSOR  32896u      // u32 [16384]
#define OFF_SRCS    49344u      // i32 [E]
#define OFF_DINV    573632u     // f32 [16384]
#define OFF_XW1     590080u     // f32 [N*32]; reused as zhl bf16 [N*32] after conv1
#define OFF_XW23    1114368u    // f32 [N*32]  (cols 0..15 = h1@W2, 16..31 = h1@W3)

__device__ __forceinline__ float sigf(float x) {
    float e = __expf(-x);
    return __builtin_amdgcn_rcpf(1.0f + e);
}

__device__ __forceinline__ unsigned short bf16_rne(float f) {
    unsigned u = __float_as_uint(f);
    return (unsigned short)((u + 0x7FFFu + ((u >> 16) & 1u)) >> 16);
}

// K1: histogram of dst
__global__ __launch_bounds__(256) void hist_k(const int* __restrict__ ei,
                                              unsigned* __restrict__ cnt) {
    int e = blockIdx.x * 256 + threadIdx.x;
    atomicAdd(&cnt[ei[N_EDGE + e]], 1u);
}

// K2: exclusive scan of cnt -> rowptr/cursor; dinv = rsqrt(cnt+1)
__global__ __launch_bounds__(1024) void scan_k(const unsigned* __restrict__ cnt,
                                               unsigned* __restrict__ rowptr,
                                               unsigned* __restrict__ cursor,
                                               float* __restrict__ dinv) {
    const int t = threadIdx.x;           // 1024 threads, 16 elems each
    unsigned vals[16];
    const uint4* c4 = (const uint4*)cnt;
#pragma unroll
    for (int i = 0; i < 4; ++i) {
        uint4 v = c4[t * 4 + i];
        vals[i * 4 + 0] = v.x; vals[i * 4 + 1] = v.y;
        vals[i * 4 + 2] = v.z; vals[i * 4 + 3] = v.w;
    }
    unsigned loc[16], s = 0;
#pragma unroll
    for (int i = 0; i < 16; ++i) { loc[i] = s; s += vals[i]; }

    const int lane = t & 63, w = t >> 6;       // 16 waves
    unsigned v = s;
#pragma unroll
    for (int off = 1; off < 64; off <<= 1) {
        unsigned u = __shfl_up(v, off);
        if (lane >= off) v += u;
    }
    __shared__ unsigned wtot[16];
    if (lane == 63) wtot[w] = v;
    __syncthreads();
    if (t == 0) {
        unsigned run = 0;
#pragma unroll
        for (int i = 0; i < 16; ++i) { unsigned x = wtot[i]; wtot[i] = run; run += x; }
        rowptr[N_NODES] = run;   // == E
    }
    __syncthreads();
    unsigned base = wtot[w] + v - s;    // exclusive prefix for this thread's chunk
#pragma unroll
    for (int i = 0; i < 16; ++i) {
        unsigned rp = base + loc[i];
        rowptr[t * 16 + i] = rp;
        cursor[t * 16 + i] = rp;
        dinv[t * 16 + i] = rsqrtf((float)(vals[i] + 1u));
    }
}

// K3: counting-sort fill: srcs grouped by dst
__global__ __launch_bounds__(256) void fill_k(const int* __restrict__ ei,
                                              unsigned* __restrict__ cursor,
                                              int* __restrict__ srcs) {
    int e = blockIdx.x * 256 + threadIdx.x;
    int d = ei[N_EDGE + e];
    unsigned p = atomicAdd(&cursor[d], 1u);
    srcs[p] = ei[e];
}

// K4: xw1 = x @ W1   [16384,512]x[512,32]
__global__ __launch_bounds__(256) void gemm1_k(const float* __restrict__ x,
                                               const float* __restrict__ W,
                                               float* __restrict__ xw) {
    int tid = blockIdx.x * 256 + threadIdx.x;
    int row = tid >> 3, cq = tid & 7;        // col quad
    const float4* x4 = (const float4*)(x + (size_t)row * F_IN);
    const float4* W4 = (const float4*)W;     // W[k][c]: 8 float4 per k-row
    float ax = 0.f, ay = 0.f, az = 0.f, aw = 0.f;
#pragma unroll 4
    for (int k4 = 0; k4 < F_IN / 4; ++k4) {
        float4 xv = x4[k4];
        float4 w0 = W4[(size_t)(4 * k4 + 0) * 8 + cq];
        float4 w1 = W4[(size_t)(4 * k4 + 1) * 8 + cq];
        float4 w2 = W4[(size_t)(4 * k4 + 2) * 8 + cq];
        float4 w3 = W4[(size_t)(4 * k4 + 3) * 8 + cq];
        ax = fmaf(xv.x, w0.x, ax); ay = fmaf(xv.x, w0.y, ay);
        az = fmaf(xv.x, w0.z, az); aw = fmaf(xv.x, w0.w, aw);
        ax = fmaf(xv.y, w1.x, ax); ay = fmaf(xv.y, w1.y, ay);
        az = fmaf(xv.y, w1.z, az); aw = fmaf(xv.y, w1.w, aw);
        ax = fmaf(xv.z, w2.x, ax); ay = fmaf(xv.z, w2.y, ay);
        az = fmaf(xv.z, w2.z, az); aw = fmaf(xv.z, w2.w, aw);
        ax = fmaf(xv.w, w3.x, ax); ay = fmaf(xv.w, w3.y, ay);
        az = fmaf(xv.w, w3.z, az); aw = fmaf(xv.w, w3.w, aw);
    }
    float4 o; o.x = ax; o.y = ay; o.z = az; o.w = aw;
    ((float4*)xw)[(size_t)row * 8 + cq] = o;
}

// K5: conv1 gather (h1 in LDS) fused with xw23 = h1@[W2|W3] (interleaved table)
__global__ __launch_bounds__(256) void conv1_k(const float* __restrict__ xw1,
                                               const float* __restrict__ dinv,
                                               const int* __restrict__ srcs,
                                               const unsigned* __restrict__ rowptr,
                                               const float* __restrict__ b1,
                                               const float* __restrict__ W2,
                                               const float* __restrict__ W3,
                                               float* __restrict__ xw23) {
    const int t = threadIdx.x;
    const int node = blockIdx.x * 8 + (t >> 5);
    const int c = t & 31;
    unsigned e0 = rowptr[node], e1 = rowptr[node + 1];
    float sum = 0.f;
    for (unsigned e = e0; e < e1; ++e) {
        int s = srcs[e];
        sum = fmaf(xw1[(size_t)s * H1 + c], dinv[s], sum);
    }
    float di = dinv[node];
    float h = fmaf(di, sum, di * di * xw1[(size_t)node * H1 + c]) + b1[c];
    __shared__ float h1s[8][H1 + 1];
    h1s[t >> 5][c] = h;
    __syncthreads();
    const float* Wm = (c < H2) ? W2 : W3;
    int q = c & (H2 - 1);
    float acc = 0.f;
#pragma unroll
    for (int k = 0; k < H1; ++k) acc = fmaf(h1s[t >> 5][k], Wm[k * H2 + q], acc);
    xw23[(size_t)node * 32 + c] = acc;
}

// K6: conv2 gather -> mu, logvar; mu lanes also emit hi/lo bf16 into zhl
// (fused former split_k).
__global__ __launch_bounds__(256) void conv2_k(const float* __restrict__ xw23,
                                               const float* __restrict__ dinv,
                                               const int* __restrict__ srcs,
                                               const unsigned* __restrict__ rowptr,
                                               const float* __restrict__ b2,
                                               const float* __restrict__ b3,
                                               float* __restrict__ out_mu,
                                               float* __restrict__ out_lv,
                                               unsigned short* __restrict__ zhl) {
    const int t = threadIdx.x;
    const int node = blockIdx.x * 8 + (t >> 5);
    const int c = t & 31;
    const int q = c & (H2 - 1);
    unsigned e0 = rowptr[node], e1 = rowptr[node + 1];
    float sum = 0.f;
    for (unsigned e = e0; e < e1; ++e) {
        int s = srcs[e];
        sum = fmaf(xw23[(size_t)s * 32 + c], dinv[s], sum);
    }
    float di = dinv[node];
    float v = fmaf(di, sum, di * di * xw23[(size_t)node * 32 + c]) +
              ((c < H2) ? b2[q] : b3[q]);
    if (c < H2) {
        out_mu[(size_t)node * H2 + q] = v;
        unsigned short hb = bf16_rne(v);
        float hf = __uint_as_float((unsigned)hb << 16);
        unsigned short lb = bf16_rne(v - hf);
        zhl[(size_t)node * 32 + q] = hb;          // hi[0..15]
        zhl[(size_t)node * 32 + 16 + q] = lb;     // lo[0..15]
    } else {
        out_lv[(size_t)node * H2 + q] = v;
    }
}

// K7: adj = sigmoid(z z^T), swapped-operand MFMA + per-wave LDS retile so
// every nt store instruction covers one aligned 1KB span of a SINGLE row.
// XOR-swizzled LDS (write: base^((lrow&7)<<2); read: lane*4^((r&7)<<2) which
// recovers logical col = lane*4 — store global at the LOGICAL column).
// Intra-wave LDS deps only -> no barriers.
__global__ __launch_bounds__(256) void adj_k(const unsigned short* __restrict__ zhl,
                                             float* __restrict__ out) {
    __shared__ float tl[4][16 * 256];   // 64KB exactly
    const int t = threadIdx.x;
    const int wave = t >> 6, lane = t & 63;
    const int lrow = lane & 15, g = lane >> 4;
    const int row0 = blockIdx.y << 6;       // 64 rows/block (16/wave)
    const int col0 = blockIdx.x << 8;       // 256 cols/block
    const short* zs = (const short*)zhl;
    const int rbase = row0 + wave * 16;
    float* L = &tl[wave][0];

    // B-frags: the wave's 16 fixed rows, [hi_r|hi_r] and [lo_r|lo_r]
    const short* rb = zs + (size_t)(rbase + lrow) * 32;
    bf16x8 B1 = *(const bf16x8*)(rb + (g & 1) * 8);
    bf16x8 B2 = *(const bf16x8*)(rb + 16 + (g & 1) * 8);

    // compute 16 col-subtiles; D: row = lane&15 (N-side), col = g*4+reg (M)
#pragma unroll
    for (int n = 0; n < 16; ++n) {
        int c = col0 + n * 16;
        bf16x8 A = *(const bf16x8*)(zs + (size_t)(c + lrow) * 32 + g * 8);
        f32x4 acc = (f32x4){0.f, 0.f, 0.f, 0.f};
        acc = __builtin_amdgcn_mfma_f32_16x16x32_bf16(A, B1, acc, 0, 0, 0);
        acc = __builtin_amdgcn_mfma_f32_16x16x32_bf16(A, B2, acc, 0, 0, 0);
        int off = (n * 16 + g * 4) ^ ((lrow & 7) << 2);   // physical = logical^swz
        *(f32x4*)&L[lrow * 256 + off] = acc;
    }

    // read back one FULL row (1KB) per wave instruction; the value at
    // physical lane*4^swz has LOGICAL column lane*4 -> store there.
#pragma unroll
    for (int r = 0; r < 16; ++r) {
        int off = (lane * 4) ^ ((r & 7) << 2);
        f32x4 v = *(const f32x4*)&L[r * 256 + off];
        f32x4 o;
        o.x = sigf(v.x); o.y = sigf(v.y); o.z = sigf(v.z); o.w = sigf(v.w);
        __builtin_nontemporal_store(
            o, (f32x4*)(out + (size_t)(rbase + r) * N_NODES + col0 + lane * 4));
    }
}

extern "C" void kernel_launch(void* const* d_in, const int* in_sizes, int n_in,
                              void* d_out, int out_size, void* d_ws, size_t ws_size,
                              hipStream_t stream) {
    const float* x  = (const float*)d_in[0];
    const int*   ei = (const int*)d_in[1];
    const float* W1 = (const float*)d_in[2];
    const float* b1 = (const float*)d_in[3];
    const float* W2 = (const float*)d_in[4];
    const float* b2 = (const float*)d_in[5];
    const float* W3 = (const float*)d_in[6];
    const float* b3 = (const float*)d_in[7];
    float* out = (float*)d_out;

    unsigned* ws   = (unsigned*)d_ws;
    unsigned* cnt    = ws + OFF_CNT;
    unsigned* rowptr = ws + OFF_ROWPTR;
    unsigned* cursor = ws + OFF_CURSOR;
    int*      srcs   = (int*)(ws + OFF_SRCS);
    float*    dinv   = (float*)(ws + OFF_DINV);
    float*    xw1    = (float*)(ws + OFF_XW1);
    float*    xw23   = (float*)(ws + OFF_XW23);
    unsigned short* zhl = (unsigned short*)(ws + OFF_XW1);  // reuse after conv1

    float* out_mu = out + (size_t)N_NODES * N_NODES;
    float* out_lv = out_mu + (size_t)N_NODES * H2;

    (void)hipMemsetAsync(cnt, 0, N_NODES * sizeof(unsigned), stream);
    hist_k<<<N_EDGE / 256, 256, 0, stream>>>(ei, cnt);
    scan_k<<<1, 1024, 0, stream>>>(cnt, rowptr, cursor, dinv);
    fill_k<<<N_EDGE / 256, 256, 0, stream>>>(ei, cursor, srcs);
    gemm1_k<<<(N_NODES * 8) / 256, 256, 0, stream>>>(x, W1, xw1);
    conv1_k<<<N_NODES / 8, 256, 0, stream>>>(xw1, dinv, srcs, rowptr, b1, W2, W3, xw23);
    conv2_k<<<N_NODES / 8, 256, 0, stream>>>(xw23, dinv, srcs, rowptr, b2, b3,
                                             out_mu, out_lv, zhl);
    adj_k<<<dim3(N_NODES / 256, N_NODES / 64), 256, 0, stream>>>(zhl, out);
}